// Round 11
// baseline (1165.867 us; speedup 1.0000x reference)
//
#include <hip/hip_runtime.h>
#include <hip/hip_bf16.h>
#include <hip/hip_fp16.h>

#define N_NODES 50000
#define N_EDGES 800000
#define NNIN    128
#define NOPEN   64
#define NUM_OUT 40
#define NLAYER  8
#define H2      0.01f

#define SCAN_BLOCKS ((N_NODES + 255) / 256)   // 196
#define NBKT ((N_NODES + 3) >> 2)             // 12500 buckets (node>>2)
#define BCAP 512                              // mean 128, sigma ~11 -> 34 sigma

// tanh(x) = 1 - 2/(exp(2x)+1); |rel err| ~1e-6.
__device__ __forceinline__ float ftanh(float x) {
    float e2 = __expf(2.0f * x);
    return 1.0f - 2.0f * __builtin_amdgcn_rcpf(e2 + 1.0f);
}

// ---- prep: degree for GCN norm (J-based + self-loop) -------------------

__global__ void deg_init(int* __restrict__ degi, int* __restrict__ deg2) {
    int n = blockIdx.x * 256 + threadIdx.x;
    if (n < N_NODES) { degi[n] = 1; deg2[n] = 0; }
}

__global__ void deg_count(const int* __restrict__ I, const int* __restrict__ J,
                          int* __restrict__ degi, int* __restrict__ deg2) {
    int e = blockIdx.x * 256 + threadIdx.x;
    if (e < N_EDGES) {
        atomicAdd(&degi[J[e]], 1);      // norm degree (reference: segment_sum over J2)
        atomicAdd(&deg2[I[e]], 1);      // structural degree, both directions
        atomicAdd(&deg2[J[e]], 1);
    }
}

__global__ void calc_dinv(const int* __restrict__ degi, float* __restrict__ dinv) {
    int n = blockIdx.x * 256 + threadIdx.x;
    if (n < N_NODES) dinv[n] = rsqrtf((float)degi[n]);
}

// ---- hierarchical exclusive scan of PADDED deg2 -> row_start -----------
// rows padded to multiples of 4 so gather's int4 entry loads are aligned.

__global__ __launch_bounds__(256) void scan1(const int* __restrict__ deg2,
                                             int* __restrict__ row_start,
                                             int* __restrict__ block_sums) {
    __shared__ int sh[256];
    int t = threadIdx.x, n = blockIdx.x * 256 + t;
    int v = (n < N_NODES) ? ((deg2[n] + 3) & ~3) : 0;
    sh[t] = v;
    __syncthreads();
#pragma unroll
    for (int off = 1; off < 256; off <<= 1) {
        int x = (t >= off) ? sh[t - off] : 0;
        __syncthreads();
        sh[t] += x;
        __syncthreads();
    }
    if (n < N_NODES) row_start[n] = sh[t] - v;  // exclusive
    if (t == 255) block_sums[blockIdx.x] = sh[t];
}

__global__ __launch_bounds__(256) void scan2(int* __restrict__ block_sums,
                                             int* __restrict__ block_off) {
    __shared__ int sh[256];
    int t = threadIdx.x;
    int v = (t < SCAN_BLOCKS) ? block_sums[t] : 0;
    sh[t] = v;
    __syncthreads();
#pragma unroll
    for (int off = 1; off < 256; off <<= 1) {
        int x = (t >= off) ? sh[t - off] : 0;
        __syncthreads();
        sh[t] += x;
        __syncthreads();
    }
    if (t < SCAN_BLOCKS) block_off[t] = sh[t] - v;  // exclusive
}

__global__ __launch_bounds__(256) void scan3(int* __restrict__ row_start,
                                             const int* __restrict__ block_off) {
    int t = threadIdx.x, n = blockIdx.x * 256 + t;
    if (n < N_NODES) row_start[n] += block_off[blockIdx.x];
}

// ---- pad rows to x4 with self-index (contributes exactly 0 in gather) --
__global__ void pad_fill(const int* __restrict__ row_start,
                         const int* __restrict__ deg2,
                         int* __restrict__ ent) {
    int n = blockIdx.x * 256 + threadIdx.x;
    if (n >= N_NODES) return;
    int beg = row_start[n], d = deg2[n];
    int end4 = beg + ((d + 3) & ~3);
    for (int p = beg + d; p < end4; p++) ent[p] = n;
}

// ---- bucketed CSR build: bucket = node>>2 (4 nodes, mean 128 entries) --

__global__ void bucket_count(const int* __restrict__ deg2, int* __restrict__ bcnt) {
    int b = blockIdx.x * 256 + threadIdx.x;
    if (b < NBKT) {
        int base = b << 2;
        int s = 0;
#pragma unroll
        for (int i = 0; i < 4; i++) {
            int n = base + i;
            s += (n < N_NODES) ? deg2[n] : 0;
        }
        bcnt[b] = s;
    }
}

// single-block exclusive scan over NBKT buckets; writes bk_start[NBKT+1], bcur
__global__ __launch_bounds__(256) void bucket_scan(const int* __restrict__ bcnt,
                                                   int* __restrict__ bk_start,
                                                   int* __restrict__ bcur) {
    __shared__ int sh[256];
    __shared__ int carry;
    int t = threadIdx.x;
    if (t == 0) carry = 0;
    __syncthreads();
    for (int c0 = 0; c0 < NBKT; c0 += 256) {
        int idx = c0 + t;
        int v = (idx < NBKT) ? bcnt[idx] : 0;
        sh[t] = v;
        __syncthreads();
        for (int off = 1; off < 256; off <<= 1) {
            int x = (t >= off) ? sh[t - off] : 0;
            __syncthreads();
            sh[t] += x;
            __syncthreads();
        }
        int excl = sh[t] - v + carry;
        if (idx < NBKT) { bk_start[idx] = excl; bcur[idx] = excl; }
        __syncthreads();
        if (t == 255) carry += sh[255];
        __syncthreads();
    }
    if (t == 0) bk_start[NBKT] = carry;   // = 2*N_EDGES
}

// Phase A: scatter packed (local<<16)|other into per-bucket regions
// (12.5k cursors: ~128 atomics/address; open-line set ~800 KB, L2-hot)
__global__ void fill_bucket(const int* __restrict__ I, const int* __restrict__ J,
                            int* __restrict__ bcur, unsigned* __restrict__ ebuf) {
    int e = blockIdx.x * 256 + threadIdx.x;
    if (e >= N_EDGES) return;
    int i = I[e], j = J[e];
    int p1 = atomicAdd(&bcur[i >> 2], 1);
    ebuf[p1] = ((unsigned)(i & 3) << 16) | (unsigned)j;
    int p2 = atomicAdd(&bcur[j >> 2], 1);
    ebuf[p2] = ((unsigned)(j & 3) << 16) | (unsigned)i;
}

// Phase B: per-bucket LDS counting sort -> final CSR ent (dense writes:
// each bucket's 4 rows are contiguous in ent)
__global__ __launch_bounds__(256) void bucket_to_csr(const unsigned* __restrict__ ebuf,
                                                     const int* __restrict__ bk_start,
                                                     const int* __restrict__ row_start,
                                                     int* __restrict__ ent) {
    __shared__ unsigned eb[BCAP];
    __shared__ int cur[4];
    int b = blockIdx.x, t = threadIdx.x;
    int s = bk_start[b];
    int cnt = bk_start[b + 1] - s;
    if (cnt > BCAP) cnt = BCAP;   // statistically unreachable (34 sigma)
    for (int i = t; i < cnt; i += 256) eb[i] = ebuf[s + i];
    if (t < 4) {
        int n = (b << 2) + t;
        cur[t] = (n < N_NODES) ? row_start[n] : 0;
    }
    __syncthreads();
    for (int i = t; i < cnt; i += 256) {
        unsigned v = eb[i];
        int ln = (int)(v >> 16) & 3;
        int p = atomicAdd(&cur[ln], 1);
        ent[p] = (int)(v & 0xffffu);
    }
}

// ---- first layer: x = relu(K1 @ xn_in), xn_in is (128, N) f32 ----------
// out layout node-major: x[n*64 + o]
__global__ __launch_bounds__(256) void first_layer(const float* __restrict__ xn,
                                                   const float* __restrict__ k1f,
                                                   float* __restrict__ x_cur,
                                                   float* __restrict__ x_old) {
    __shared__ float Ks[NOPEN * 129];
    __shared__ float xs[32 * 64];
    int t = threadIdx.x;
    int n0 = blockIdx.x * 64;
    for (int idx = t; idx < NOPEN * NNIN; idx += 256)
        Ks[(idx >> 7) * 129 + (idx & 127)] = k1f[idx];

    int tn = t & 15, to = t >> 4;
    float acc[4][4] = {};
    for (int c0 = 0; c0 < NNIN; c0 += 32) {
        __syncthreads();
        for (int idx = t; idx < 32 * 64; idx += 256) {
            int ci = idx >> 6, n = idx & 63;
            int gn = n0 + n;
            xs[ci * 64 + n] = (gn < N_NODES) ? xn[(size_t)(c0 + ci) * N_NODES + gn] : 0.f;
        }
        __syncthreads();
        for (int ci = 0; ci < 32; ci++) {
            float xv[4], kv[4];
#pragma unroll
            for (int i2 = 0; i2 < 4; i2++) xv[i2] = xs[ci * 64 + tn * 4 + i2];
#pragma unroll
            for (int j = 0; j < 4; j++) kv[j] = Ks[(to * 4 + j) * 129 + c0 + ci];
#pragma unroll
            for (int i2 = 0; i2 < 4; i2++)
#pragma unroll
                for (int j = 0; j < 4; j++) acc[i2][j] += xv[i2] * kv[j];
        }
    }
#pragma unroll
    for (int i2 = 0; i2 < 4; i2++) {
        int node = n0 + tn * 4 + i2;
        if (node < N_NODES) {
            float4 st;
            st.x = fmaxf(acc[i2][0], 0.f);
            st.y = fmaxf(acc[i2][1], 0.f);
            st.z = fmaxf(acc[i2][2], 0.f);
            st.w = fmaxf(acc[i2][3], 0.f);
            *(float4*)&x_cur[(size_t)node * 64 + to * 4] = st;
            *(float4*)&x_old[(size_t)node * 64 + to * 4] = st;
        }
    }
}

// ---- Y[n][o] = sum_c K[o][c] * x[n][c], output fp16 --------------------
__global__ __launch_bounds__(256) void mat_y(const float* __restrict__ x,
                                             const float* __restrict__ K,
                                             __half* __restrict__ Y) {
    __shared__ float Ks[64 * 65];
    __shared__ float xs[64 * 65];
    int t = threadIdx.x, n0 = blockIdx.x * 64;
    for (int idx = t; idx < 4096; idx += 256) {
        int r = idx >> 6, c = idx & 63;
        Ks[r * 65 + c] = K[idx];
        int gn = n0 + r;
        xs[r * 65 + c] = (gn < N_NODES) ? x[(size_t)gn * 64 + c] : 0.f;
    }
    __syncthreads();
    int tn = t & 15, to = t >> 4;
    float acc[4][4] = {};
    for (int c = 0; c < 64; c++) {
        float xv[4], kv[4];
#pragma unroll
        for (int i2 = 0; i2 < 4; i2++) xv[i2] = xs[(tn * 4 + i2) * 65 + c];
#pragma unroll
        for (int j = 0; j < 4; j++) kv[j] = Ks[(to * 4 + j) * 65 + c];
#pragma unroll
        for (int i2 = 0; i2 < 4; i2++)
#pragma unroll
            for (int j = 0; j < 4; j++) acc[i2][j] += xv[i2] * kv[j];
    }
#pragma unroll
    for (int i2 = 0; i2 < 4; i2++) {
        int node = n0 + tn * 4 + i2;
        if (node < N_NODES) {
            __half2 h0 = __floats2half2_rn(acc[i2][0], acc[i2][1]);
            __half2 h1 = __floats2half2_rn(acc[i2][2], acc[i2][3]);
            __half2* dst = (__half2*)&Y[(size_t)node * 64 + to * 4];
            dst[0] = h0;
            dst[1] = h1;
        }
    }
}

// ---- fused gather + update: 16 waves/block, 1 wave per node ------------
// Split-wave pairing (R10); x streams non-temporal to keep Y L2-resident.
__global__ __launch_bounds__(1024) void gather_update(const __half* __restrict__ Y,
                                                      const float* __restrict__ x_cur,
                                                      const float* __restrict__ x_old,
                                                      const int* __restrict__ ent,
                                                      const int* __restrict__ row_start,
                                                      const int* __restrict__ deg2,
                                                      const float* __restrict__ dinv,
                                                      const float* __restrict__ K,
                                                      float* __restrict__ x_out) {
    __shared__ float Ks[64 * 65];   // K[c][o] at Ks[c*65+o]
    __shared__ float Ss[16][64];
    int t = threadIdx.x;
    for (int idx = t; idx < 4096; idx += 1024)
        Ks[(idx >> 6) * 65 + (idx & 63)] = K[idx];

    int wv = t >> 6, lane = t & 63;
    int n = blockIdx.x * 16 + wv;
    int c2  = lane & 31;        // channel-pair index (channels 2*c2, 2*c2+1)
    int sel = lane >> 5;        // 0: even entries, 1: odd entries
    float sx = 0.f, sy = 0.f;
    if (n < N_NODES) {
        const __half2 ynh = *(const __half2*)&Y[((size_t)n << 6) + 2 * c2];
        float ynx = __half2float(__low2half(ynh));
        float yny = __half2float(__high2half(ynh));
        float vn = dinv[n];
        int beg = __builtin_amdgcn_readfirstlane(row_start[n]);  // % 4 == 0
        int d   = __builtin_amdgcn_readfirstlane(deg2[n]);
        int end = beg + ((d + 3) & ~3);                          // padded, no tail
        for (int k = beg; k < end; k += 4) {
            int4 oo = *(const int4*)&ent[k];               // 16B-aligned, uniform
            int o0 = __builtin_amdgcn_readfirstlane(oo.x);
            int o1 = __builtin_amdgcn_readfirstlane(oo.y);
            int o2 = __builtin_amdgcn_readfirstlane(oo.z);
            int o3 = __builtin_amdgcn_readfirstlane(oo.w);
            int oa = sel ? o1 : o0;                        // pair 0: entries k,k+1
            int ob = sel ? o3 : o2;                        // pair 1: entries k+2,k+3
            const __half2 ha = *(const __half2*)&Y[((size_t)oa << 6) + 2 * c2];
            const __half2 hb = *(const __half2*)&Y[((size_t)ob << 6) + 2 * c2];
            float wa = dinv[oa] * vn;
            float wb = dinv[ob] * vn;
            float ax = __half2float(__low2half(ha)), ay = __half2float(__high2half(ha));
            float bx = __half2float(__low2half(hb)), by = __half2float(__high2half(hb));
            sx += wa * ftanh(wa * (ynx - ax));
            sy += wa * ftanh(wa * (yny - ay));
            sx += wb * ftanh(wb * (ynx - bx));
            sy += wb * ftanh(wb * (yny - by));
        }
    }
    // merge even/odd halves: partner lane is lane ^ 32
    sx += __shfl_xor(sx, 32, 64);
    sy += __shfl_xor(sy, 32, 64);
    if (lane < 32) {
        Ss[wv][2 * c2]     = sx;
        Ss[wv][2 * c2 + 1] = sy;
    }
    __syncthreads();
    if (n < N_NODES) {
        float acc = 0.f;
#pragma unroll 8
        for (int o = 0; o < 64; o++)
            acc += Ks[lane * 65 + o] * Ss[wv][o];   // 2-way bank alias (free) + broadcast
        float xc = __builtin_nontemporal_load(&x_cur[(size_t)n * 64 + lane]);
        float xo = __builtin_nontemporal_load(&x_old[(size_t)n * 64 + lane]);
        __builtin_nontemporal_store(2.f * xc - xo - H2 * acc,
                                    &x_out[(size_t)n * 64 + lane]);
    }
}

// ---- out[n][o] = sum_c KNc[o][c] * x[n][c]; out is (N,40) f32 ----------
__global__ __launch_bounds__(256) void out_kernel(const float* __restrict__ x,
                                                  const float* __restrict__ Kc,
                                                  float* __restrict__ out) {
    __shared__ float xs[64 * 65];
    __shared__ float Ks[40 * 65];
    int t = threadIdx.x, n0 = blockIdx.x * 64;
    for (int idx = t; idx < 4096; idx += 256) {
        int r = idx >> 6, c = idx & 63;
        int gn = n0 + r;
        xs[r * 65 + c] = (gn < N_NODES) ? x[(size_t)gn * 64 + c] : 0.f;
    }
    for (int idx = t; idx < NUM_OUT * 64; idx += 256) {
        int r = idx >> 6, c = idx & 63;
        Ks[r * 65 + c] = Kc[idx];
    }
    __syncthreads();
    if (t < 160) {
        int tn = t & 15, to = t >> 4;
        float acc[4][4] = {};
        for (int c = 0; c < 64; c++) {
            float xv[4], kv[4];
#pragma unroll
            for (int i2 = 0; i2 < 4; i2++) xv[i2] = xs[(tn * 4 + i2) * 65 + c];
#pragma unroll
            for (int j = 0; j < 4; j++) kv[j] = Ks[(to * 4 + j) * 65 + c];
#pragma unroll
            for (int i2 = 0; i2 < 4; i2++)
#pragma unroll
                for (int j = 0; j < 4; j++) acc[i2][j] += xv[i2] * kv[j];
        }
#pragma unroll
        for (int i2 = 0; i2 < 4; i2++) {
            int node = n0 + tn * 4 + i2;
            if (node < N_NODES) {
#pragma unroll
                for (int j = 0; j < 4; j++)
                    out[(size_t)node * NUM_OUT + to * 4 + j] = acc[i2][j];
            }
        }
    }
}

extern "C" void kernel_launch(void* const* d_in, const int* in_sizes, int n_in,
                              void* d_out, int out_size, void* d_ws, size_t ws_size,
                              hipStream_t stream) {
    const float* xn = (const float*)d_in[0];
    const int*   I  = (const int*)d_in[1];
    const int*   J  = (const int*)d_in[2];
    const float* K1 = (const float*)d_in[4];
    const float* K2 = (const float*)d_in[5];
    const float* Kc = (const float*)d_in[6];

    const size_t NC = (size_t)N_NODES * NOPEN;  // 3.2M
    float*    f      = (float*)d_ws;
    float*    x_cur  = f;
    float*    x_old  = f + NC;
    __half*   Y      = (__half*)(f + 2 * NC);     // 6.4 MB
    float*    dinv   = f + 2 * NC + NC / 2;
    int*      degi   = (int*)(dinv + N_NODES);
    int*      deg2   = degi + N_NODES;
    int*      row_st = deg2 + N_NODES;
    int*      bsums  = row_st + N_NODES;
    int*      boff   = bsums + 256;
    int*      bcnt   = boff + 256;
    int*      bk_st  = bcnt + NBKT;               // NBKT+1
    int*      bcur   = bk_st + NBKT + 1;
    unsigned* ebuf   = (unsigned*)(bcur + NBKT);  // 1.6M u32 = 6.4 MB
    int*      ent    = (int*)(ebuf + 2 * (size_t)N_EDGES);  // <= 2E+4N ints

    dim3 B(256);
    const int GN = (N_NODES + 255) / 256;   // 196
    const int GE = (N_EDGES + 255) / 256;

    deg_init<<<GN, B, 0, stream>>>(degi, deg2);
    deg_count<<<GE, B, 0, stream>>>(I, J, degi, deg2);
    calc_dinv<<<GN, B, 0, stream>>>(degi, dinv);
    scan1<<<SCAN_BLOCKS, B, 0, stream>>>(deg2, row_st, bsums);
    scan2<<<1, B, 0, stream>>>(bsums, boff);
    scan3<<<SCAN_BLOCKS, B, 0, stream>>>(row_st, boff);
    bucket_count<<<(NBKT + 255) / 256, B, 0, stream>>>(deg2, bcnt);
    bucket_scan<<<1, B, 0, stream>>>(bcnt, bk_st, bcur);
    fill_bucket<<<GE, B, 0, stream>>>(I, J, bcur, ebuf);
    pad_fill<<<GN, B, 0, stream>>>(row_st, deg2, ent);
    bucket_to_csr<<<NBKT, B, 0, stream>>>(ebuf, bk_st, row_st, ent);

    const int NB = (N_NODES + 63) / 64;     // 782
    first_layer<<<NB, B, 0, stream>>>(xn, K1, x_cur, x_old);

    float* xc = x_cur;
    float* xo = x_old;
    for (int l = 0; l < NLAYER; l++) {
        mat_y<<<NB, B, 0, stream>>>(xc, K2 + l * NOPEN * NOPEN, Y);
        gather_update<<<(N_NODES + 15) / 16, dim3(1024), 0, stream>>>(
            Y, xc, xo, ent, row_st, deg2, dinv, K2 + l * NOPEN * NOPEN, xo);
        float* tmp = xc; xc = xo; xo = tmp;
    }
    out_kernel<<<NB, B, 0, stream>>>(xc, Kc, (float*)d_out);
}

// Round 12
// 1055.364 us; speedup vs baseline: 1.1047x; 1.1047x over previous
//
#include <hip/hip_runtime.h>
#include <hip/hip_bf16.h>
#include <hip/hip_fp16.h>

#define N_NODES 50000
#define N_EDGES 800000
#define NNIN    128
#define NOPEN   64
#define NUM_OUT 40
#define NLAYER  8
#define H2      0.01f

#define SCAN_BLOCKS ((N_NODES + 255) / 256)   // 196

// tanh(x) = 1 - 2/(exp(2x)+1); |rel err| ~1e-6.
__device__ __forceinline__ float ftanh(float x) {
    float e2 = __expf(2.0f * x);
    return 1.0f - 2.0f * __builtin_amdgcn_rcpf(e2 + 1.0f);
}

// ---- prep: degree for GCN norm (J-based + self-loop) -------------------

__global__ void deg_init(int* __restrict__ degi, int* __restrict__ deg2) {
    int n = blockIdx.x * 256 + threadIdx.x;
    if (n < N_NODES) { degi[n] = 1; deg2[n] = 0; }
}

__global__ void deg_count(const int* __restrict__ I, const int* __restrict__ J,
                          int* __restrict__ degi, int* __restrict__ deg2) {
    int e = blockIdx.x * 256 + threadIdx.x;
    if (e < N_EDGES) {
        atomicAdd(&degi[J[e]], 1);      // norm degree (reference: segment_sum over J2)
        atomicAdd(&deg2[I[e]], 1);      // structural degree, both directions
        atomicAdd(&deg2[J[e]], 1);
    }
}

__global__ void calc_dinv(const int* __restrict__ degi, float* __restrict__ dinv) {
    int n = blockIdx.x * 256 + threadIdx.x;
    if (n < N_NODES) dinv[n] = rsqrtf((float)degi[n]);
}

// ---- hierarchical exclusive scan of PADDED deg2 -> row_start -----------
// rows padded to multiples of 4 so gather's int4 entry loads are aligned.

__global__ __launch_bounds__(256) void scan1(const int* __restrict__ deg2,
                                             int* __restrict__ row_start,
                                             int* __restrict__ block_sums) {
    __shared__ int sh[256];
    int t = threadIdx.x, n = blockIdx.x * 256 + t;
    int v = (n < N_NODES) ? ((deg2[n] + 3) & ~3) : 0;
    sh[t] = v;
    __syncthreads();
#pragma unroll
    for (int off = 1; off < 256; off <<= 1) {
        int x = (t >= off) ? sh[t - off] : 0;
        __syncthreads();
        sh[t] += x;
        __syncthreads();
    }
    if (n < N_NODES) row_start[n] = sh[t] - v;  // exclusive
    if (t == 255) block_sums[blockIdx.x] = sh[t];
}

__global__ __launch_bounds__(256) void scan2(int* __restrict__ block_sums,
                                             int* __restrict__ block_off) {
    __shared__ int sh[256];
    int t = threadIdx.x;
    int v = (t < SCAN_BLOCKS) ? block_sums[t] : 0;
    sh[t] = v;
    __syncthreads();
#pragma unroll
    for (int off = 1; off < 256; off <<= 1) {
        int x = (t >= off) ? sh[t - off] : 0;
        __syncthreads();
        sh[t] += x;
        __syncthreads();
    }
    if (t < SCAN_BLOCKS) block_off[t] = sh[t] - v;  // exclusive
}

__global__ __launch_bounds__(256) void scan3(int* __restrict__ row_start,
                                             const int* __restrict__ block_off,
                                             int* __restrict__ cursor) {
    int t = threadIdx.x, n = blockIdx.x * 256 + t;
    if (n < N_NODES) {
        int r = row_start[n] + block_off[blockIdx.x];
        row_start[n] = r;
        cursor[n] = r;
    }
}

// ---- pad rows to x4 with self-index (contributes exactly 0 in gather) --
__global__ void pad_fill(const int* __restrict__ row_start,
                         const int* __restrict__ deg2,
                         int* __restrict__ ent) {
    int n = blockIdx.x * 256 + threadIdx.x;
    if (n >= N_NODES) return;
    int beg = row_start[n], d = deg2[n];
    int end4 = beg + ((d + 3) & ~3);
    for (int p = beg + d; p < end4; p++) ent[p] = n;
}

// ---- fill CSR entries (R8-proven direct scatter) -----------------------
__global__ void fill_ent(const int* __restrict__ I, const int* __restrict__ J,
                         int* __restrict__ cursor, int* __restrict__ ent) {
    int e = blockIdx.x * 256 + threadIdx.x;
    if (e >= N_EDGES) return;
    int i = I[e], j = J[e];
    int p1 = atomicAdd(&cursor[i], 1);
    ent[p1] = j;
    int p2 = atomicAdd(&cursor[j], 1);
    ent[p2] = i;
}

// ---- first layer: x = relu(K1 @ xn_in), xn_in is (128, N) f32 ----------
__global__ __launch_bounds__(256) void first_layer(const float* __restrict__ xn,
                                                   const float* __restrict__ k1f,
                                                   float* __restrict__ x_cur,
                                                   float* __restrict__ x_old) {
    __shared__ float Ks[NOPEN * 129];
    __shared__ float xs[32 * 64];
    int t = threadIdx.x;
    int n0 = blockIdx.x * 64;
    for (int idx = t; idx < NOPEN * NNIN; idx += 256)
        Ks[(idx >> 7) * 129 + (idx & 127)] = k1f[idx];

    int tn = t & 15, to = t >> 4;
    float acc[4][4] = {};
    for (int c0 = 0; c0 < NNIN; c0 += 32) {
        __syncthreads();
        for (int idx = t; idx < 32 * 64; idx += 256) {
            int ci = idx >> 6, n = idx & 63;
            int gn = n0 + n;
            xs[ci * 64 + n] = (gn < N_NODES) ? xn[(size_t)(c0 + ci) * N_NODES + gn] : 0.f;
        }
        __syncthreads();
        for (int ci = 0; ci < 32; ci++) {
            float xv[4], kv[4];
#pragma unroll
            for (int i2 = 0; i2 < 4; i2++) xv[i2] = xs[ci * 64 + tn * 4 + i2];
#pragma unroll
            for (int j = 0; j < 4; j++) kv[j] = Ks[(to * 4 + j) * 129 + c0 + ci];
#pragma unroll
            for (int i2 = 0; i2 < 4; i2++)
#pragma unroll
                for (int j = 0; j < 4; j++) acc[i2][j] += xv[i2] * kv[j];
        }
    }
#pragma unroll
    for (int i2 = 0; i2 < 4; i2++) {
        int node = n0 + tn * 4 + i2;
        if (node < N_NODES) {
            float4 st;
            st.x = fmaxf(acc[i2][0], 0.f);
            st.y = fmaxf(acc[i2][1], 0.f);
            st.z = fmaxf(acc[i2][2], 0.f);
            st.w = fmaxf(acc[i2][3], 0.f);
            *(float4*)&x_cur[(size_t)node * 64 + to * 4] = st;
            *(float4*)&x_old[(size_t)node * 64 + to * 4] = st;
        }
    }
}

// ---- Y[n][o] = sum_c K[o][c] * x[n][c], fp16 out (layer 0 only) --------
__global__ __launch_bounds__(256) void mat_y(const float* __restrict__ x,
                                             const float* __restrict__ K,
                                             __half* __restrict__ Y) {
    __shared__ float Ks[64 * 65];
    __shared__ float xs[64 * 65];
    int t = threadIdx.x, n0 = blockIdx.x * 64;
    for (int idx = t; idx < 4096; idx += 256) {
        int r = idx >> 6, c = idx & 63;
        Ks[r * 65 + c] = K[idx];
        int gn = n0 + r;
        xs[r * 65 + c] = (gn < N_NODES) ? x[(size_t)gn * 64 + c] : 0.f;
    }
    __syncthreads();
    int tn = t & 15, to = t >> 4;
    float acc[4][4] = {};
    for (int c = 0; c < 64; c++) {
        float xv[4], kv[4];
#pragma unroll
        for (int i2 = 0; i2 < 4; i2++) xv[i2] = xs[(tn * 4 + i2) * 65 + c];
#pragma unroll
        for (int j = 0; j < 4; j++) kv[j] = Ks[(to * 4 + j) * 65 + c];
#pragma unroll
        for (int i2 = 0; i2 < 4; i2++)
#pragma unroll
            for (int j = 0; j < 4; j++) acc[i2][j] += xv[i2] * kv[j];
    }
#pragma unroll
    for (int i2 = 0; i2 < 4; i2++) {
        int node = n0 + tn * 4 + i2;
        if (node < N_NODES) {
            __half2 h0 = __floats2half2_rn(acc[i2][0], acc[i2][1]);
            __half2 h1 = __floats2half2_rn(acc[i2][2], acc[i2][3]);
            __half2* dst = (__half2*)&Y[(size_t)node * 64 + to * 4];
            dst[0] = h0;
            dst[1] = h1;
        }
    }
}

// ---- fused gather + update + next-layer Y ------------------------------
// 16 waves/block, 1 wave/node; split-wave pairing (R10).
// Epilogue: x_new = 2x_c - x_o - H2*K.S; then Y_next[o] = sum_c Kn[o][c]*x_new[c]
// (fuses next layer's mat_y; x_new staged in Ss, intra-wave only).
__global__ __launch_bounds__(1024) void gather_update(const __half* __restrict__ Y,
                                                      const float* __restrict__ x_cur,
                                                      const float* __restrict__ x_old,
                                                      const int* __restrict__ ent,
                                                      const int* __restrict__ row_start,
                                                      const int* __restrict__ deg2,
                                                      const float* __restrict__ dinv,
                                                      const float* __restrict__ K,
                                                      const float* __restrict__ Kn,
                                                      float* __restrict__ x_out,
                                                      __half* __restrict__ Y_out) {
    __shared__ float Ks[64 * 65];    // K[c][o]-access at Ks[c*65+o] (storage [dim0*65+dim1])
    __shared__ float Ksn[64 * 65];   // Kn[o][c]-access at Ksn[o*65+c]
    __shared__ float Ss[16][64];
    int t = threadIdx.x;
    for (int idx = t; idx < 4096; idx += 1024) {
        Ks[(idx >> 6) * 65 + (idx & 63)] = K[idx];
        Ksn[(idx >> 6) * 65 + (idx & 63)] = Kn[idx];
    }

    int wv = t >> 6, lane = t & 63;
    int n = blockIdx.x * 16 + wv;
    int c2  = lane & 31;        // channel-pair index (channels 2*c2, 2*c2+1)
    int sel = lane >> 5;        // 0: even entries, 1: odd entries
    float sx = 0.f, sy = 0.f;
    if (n < N_NODES) {
        const __half2 ynh = *(const __half2*)&Y[((size_t)n << 6) + 2 * c2];
        float ynx = __half2float(__low2half(ynh));
        float yny = __half2float(__high2half(ynh));
        float vn = dinv[n];
        int beg = __builtin_amdgcn_readfirstlane(row_start[n]);  // % 4 == 0
        int d   = __builtin_amdgcn_readfirstlane(deg2[n]);
        int end = beg + ((d + 3) & ~3);                          // padded, no tail
        for (int k = beg; k < end; k += 4) {
            int4 oo = *(const int4*)&ent[k];               // 16B-aligned, uniform
            int o0 = __builtin_amdgcn_readfirstlane(oo.x);
            int o1 = __builtin_amdgcn_readfirstlane(oo.y);
            int o2 = __builtin_amdgcn_readfirstlane(oo.z);
            int o3 = __builtin_amdgcn_readfirstlane(oo.w);
            int oa = sel ? o1 : o0;                        // pair 0: entries k,k+1
            int ob = sel ? o3 : o2;                        // pair 1: entries k+2,k+3
            const __half2 ha = *(const __half2*)&Y[((size_t)oa << 6) + 2 * c2];
            const __half2 hb = *(const __half2*)&Y[((size_t)ob << 6) + 2 * c2];
            float wa = dinv[oa] * vn;
            float wb = dinv[ob] * vn;
            float ax = __half2float(__low2half(ha)), ay = __half2float(__high2half(ha));
            float bx = __half2float(__low2half(hb)), by = __half2float(__high2half(hb));
            sx += wa * ftanh(wa * (ynx - ax));
            sy += wa * ftanh(wa * (yny - ay));
            sx += wb * ftanh(wb * (ynx - bx));
            sy += wb * ftanh(wb * (yny - by));
        }
    }
    // merge even/odd halves: partner lane is lane ^ 32
    sx += __shfl_xor(sx, 32, 64);
    sy += __shfl_xor(sy, 32, 64);
    __syncthreads();            // Ks/Ksn staging complete (also orders Ss reuse)
    if (lane < 32) {
        Ss[wv][2 * c2]     = sx;
        Ss[wv][2 * c2 + 1] = sy;
    }
    if (n < N_NODES) {
        float acc = 0.f;
#pragma unroll 8
        for (int o = 0; o < 64; o++)
            acc += Ks[lane * 65 + o] * Ss[wv][o];   // K storage [c=lane][o]
        float xc = x_cur[(size_t)n * 64 + lane];
        float xo = x_old[(size_t)n * 64 + lane];
        float xnew = 2.f * xc - xo - H2 * acc;
        __builtin_nontemporal_store(xnew, &x_out[(size_t)n * 64 + lane]);
        // ---- fused next-layer Y: stage x_new in Ss (intra-wave), matvec
        Ss[wv][lane] = xnew;
        float acc2 = 0.f;
#pragma unroll 8
        for (int c = 0; c < 64; c++)
            acc2 += Ksn[lane * 65 + c] * Ss[wv][c];  // Kn storage [o=lane][c]
        Y_out[((size_t)n << 6) + lane] = __float2half(acc2);
    }
}

// ---- out[n][o] = sum_c KNc[o][c] * x[n][c]; out is (N,40) f32 ----------
__global__ __launch_bounds__(256) void out_kernel(const float* __restrict__ x,
                                                  const float* __restrict__ Kc,
                                                  float* __restrict__ out) {
    __shared__ float xs[64 * 65];
    __shared__ float Ks[40 * 65];
    int t = threadIdx.x, n0 = blockIdx.x * 64;
    for (int idx = t; idx < 4096; idx += 256) {
        int r = idx >> 6, c = idx & 63;
        int gn = n0 + r;
        xs[r * 65 + c] = (gn < N_NODES) ? x[(size_t)gn * 64 + c] : 0.f;
    }
    for (int idx = t; idx < NUM_OUT * 64; idx += 256) {
        int r = idx >> 6, c = idx & 63;
        Ks[r * 65 + c] = Kc[idx];
    }
    __syncthreads();
    if (t < 160) {
        int tn = t & 15, to = t >> 4;
        float acc[4][4] = {};
        for (int c = 0; c < 64; c++) {
            float xv[4], kv[4];
#pragma unroll
            for (int i2 = 0; i2 < 4; i2++) xv[i2] = xs[(tn * 4 + i2) * 65 + c];
#pragma unroll
            for (int j = 0; j < 4; j++) kv[j] = Ks[(to * 4 + j) * 65 + c];
#pragma unroll
            for (int i2 = 0; i2 < 4; i2++)
#pragma unroll
                for (int j = 0; j < 4; j++) acc[i2][j] += xv[i2] * kv[j];
        }
#pragma unroll
        for (int i2 = 0; i2 < 4; i2++) {
            int node = n0 + tn * 4 + i2;
            if (node < N_NODES) {
#pragma unroll
                for (int j = 0; j < 4; j++)
                    out[(size_t)node * NUM_OUT + to * 4 + j] = acc[i2][j];
            }
        }
    }
}

extern "C" void kernel_launch(void* const* d_in, const int* in_sizes, int n_in,
                              void* d_out, int out_size, void* d_ws, size_t ws_size,
                              hipStream_t stream) {
    const float* xn = (const float*)d_in[0];
    const int*   I  = (const int*)d_in[1];
    const int*   J  = (const int*)d_in[2];
    const float* K1 = (const float*)d_in[4];
    const float* K2 = (const float*)d_in[5];
    const float* Kc = (const float*)d_in[6];

    const size_t NC = (size_t)N_NODES * NOPEN;  // 3.2M
    float*  f      = (float*)d_ws;
    float*  x_cur  = f;
    float*  x_old  = f + NC;
    __half* Y0     = (__half*)(f + 2 * NC);     // 6.4 MB
    __half* Y1     = (__half*)(f + 2 * NC + NC / 2);
    float*  dinv   = f + 3 * NC;
    int*    degi   = (int*)(dinv + N_NODES);
    int*    deg2   = degi + N_NODES;
    int*    row_st = deg2 + N_NODES;
    int*    cursor = row_st + N_NODES;
    int*    bsums  = cursor + N_NODES;
    int*    boff   = bsums + 256;
    int*    ent    = boff + 256;                // <= 2*E + 4*N ints = 13.6 MB

    dim3 B(256);
    const int GN = (N_NODES + 255) / 256;   // 196
    const int GE = (N_EDGES + 255) / 256;

    deg_init<<<GN, B, 0, stream>>>(degi, deg2);
    deg_count<<<GE, B, 0, stream>>>(I, J, degi, deg2);
    calc_dinv<<<GN, B, 0, stream>>>(degi, dinv);
    scan1<<<SCAN_BLOCKS, B, 0, stream>>>(deg2, row_st, bsums);
    scan2<<<1, B, 0, stream>>>(bsums, boff);
    scan3<<<SCAN_BLOCKS, B, 0, stream>>>(row_st, boff, cursor);
    pad_fill<<<GN, B, 0, stream>>>(row_st, deg2, ent);
    fill_ent<<<GE, B, 0, stream>>>(I, J, cursor, ent);

    const int NB = (N_NODES + 63) / 64;     // 782
    first_layer<<<NB, B, 0, stream>>>(xn, K1, x_cur, x_old);
    mat_y<<<NB, B, 0, stream>>>(x_cur, K2, Y0);   // Y for layer 0 only

    __half* Yin = Y0;
    __half* Yout = Y1;
    float* xc = x_cur;
    float* xo = x_old;
    for (int l = 0; l < NLAYER; l++) {
        const float* Kl = K2 + l * NOPEN * NOPEN;
        const float* Knext = K2 + (l + 1 < NLAYER ? l + 1 : l) * NOPEN * NOPEN;
        gather_update<<<(N_NODES + 15) / 16, dim3(1024), 0, stream>>>(
            Yin, xc, xo, ent, row_st, deg2, dinv, Kl, Knext, xo, Yout);
        float* tmp = xc; xc = xo; xo = tmp;
        __half* th = Yin; Yin = Yout; Yout = th;
    }
    out_kernel<<<NB, B, 0, stream>>>(xc, Kc, (float*)d_out);
}

// Round 13
// 873.413 us; speedup vs baseline: 1.3348x; 1.2083x over previous
//
#include <hip/hip_runtime.h>
#include <hip/hip_bf16.h>
#include <hip/hip_fp16.h>

#define N_NODES 50000
#define N_EDGES 800000
#define NNIN    128
#define NOPEN   64
#define NUM_OUT 40
#define NLAYER  8
#define H2      0.01f

#define NDIG  ((N_NODES + 255) >> 8)          // 196 digits (node>>8)
#define EPB   2048                            // edges per pass1/count block
#define P1B   ((N_EDGES + EPB - 1) / EPB)     // 391 blocks
#define P2CAP 9216                            // mean 8163, sigma ~90 -> +11.7 sigma

// tanh(x) = 1 - 2/(exp(2x)+1); |rel err| ~1e-6.
__device__ __forceinline__ float ftanh(float x) {
    float e2 = __expf(2.0f * x);
    return 1.0f - 2.0f * __builtin_amdgcn_rcpf(e2 + 1.0f);
}

// ---- prep ---------------------------------------------------------------

__global__ void deg_init(int* __restrict__ degi) {
    int n = blockIdx.x * 256 + threadIdx.x;
    if (n < N_NODES) degi[n] = 1;   // self-loop (norm degree)
}

// per-block LDS digit histogram + degi atomics (16/addr avg — safe);
// flush as DENSE writes to bh[b][NDIG]; zero global atomics for the hist.
__global__ __launch_bounds__(256) void count_all(const int* __restrict__ I,
                                                 const int* __restrict__ J,
                                                 int* __restrict__ degi,
                                                 int* __restrict__ bh) {
    __shared__ int h[NDIG];
    int t = threadIdx.x, b = blockIdx.x;
    for (int i = t; i < NDIG; i += 256) h[i] = 0;
    __syncthreads();
    int e0 = b * EPB;
    int e1 = min(e0 + EPB, N_EDGES);
    for (int e = e0 + t; e < e1; e += 256) {
        int i = I[e], j = J[e];
        atomicAdd(&degi[j], 1);
        atomicAdd(&h[i >> 8], 1);
        atomicAdd(&h[j >> 8], 1);
    }
    __syncthreads();
    for (int i = t; i < NDIG; i += 256) bh[b * NDIG + i] = h[i];
}

__global__ void calc_dinv(const int* __restrict__ degi, float* __restrict__ dinv) {
    int n = blockIdx.x * 256 + threadIdx.x;
    if (n < N_NODES) dinv[n] = rsqrtf((float)degi[n]);
}

// per-digit exclusive scan over blocks: off[d][b], total[d]. No atomics.
__global__ __launch_bounds__(512) void col_scan(const int* __restrict__ bh,
                                                int* __restrict__ off,
                                                int* __restrict__ total) {
    __shared__ int sh[512];
    int d = blockIdx.x, t = threadIdx.x;
    int v = (t < P1B) ? bh[t * NDIG + d] : 0;
    sh[t] = v;
    __syncthreads();
#pragma unroll
    for (int o = 1; o < 512; o <<= 1) {
        int x = (t >= o) ? sh[t - o] : 0;
        __syncthreads();
        sh[t] += x;
        __syncthreads();
    }
    if (t < P1B) off[d * P1B + t] = sh[t] - v;   // exclusive
    if (t == 511) total[d] = sh[511];
}

// digit-level scans: raw offsets (ebuf) and padded-capacity offsets (ent).
__global__ __launch_bounds__(256) void dig_scan(const int* __restrict__ total,
                                                int* __restrict__ dig_raw,
                                                int* __restrict__ dig_pad) {
    __shared__ int sh[256], sh2[256];
    int t = threadIdx.x;
    int v   = (t < NDIG) ? total[t] : 0;
    int cap = (t < NDIG) ? ((v + 768 + 3) & ~3) : 0;  // <=256 rows * 3 pad, x4 align
    sh[t] = v; sh2[t] = cap;
    __syncthreads();
#pragma unroll
    for (int o = 1; o < 256; o <<= 1) {
        int x = (t >= o) ? sh[t - o] : 0;
        int y = (t >= o) ? sh2[t - o] : 0;
        __syncthreads();
        sh[t] += x; sh2[t] += y;
        __syncthreads();
    }
    if (t < NDIG) { dig_raw[t] = sh[t] - v; dig_pad[t] = sh2[t] - cap; }
}

// pass 1: scatter packed (node<<16)|other into per-(block,digit) runs at
// PRECOMPUTED offsets — LDS atomics only; runs are block-owned => dense L2 WB.
__global__ __launch_bounds__(256) void pass1_scatter(const int* __restrict__ I,
                                                     const int* __restrict__ J,
                                                     const int* __restrict__ off,
                                                     const int* __restrict__ dig_raw,
                                                     unsigned* __restrict__ ebuf) {
    __shared__ int cnt2[NDIG];
    __shared__ int base[NDIG];
    int t = threadIdx.x, b = blockIdx.x;
    for (int i = t; i < NDIG; i += 256) {
        cnt2[i] = 0;
        base[i] = dig_raw[i] + off[i * P1B + b];
    }
    __syncthreads();
    int e0 = b * EPB;
    int e1 = min(e0 + EPB, N_EDGES);
    for (int e = e0 + t; e < e1; e += 256) {
        int i = I[e], j = J[e];
        int li = atomicAdd(&cnt2[i >> 8], 1);
        ebuf[base[i >> 8] + li] = ((unsigned)i << 16) | (unsigned)j;
        int lj = atomicAdd(&cnt2[j >> 8], 1);
        ebuf[base[j >> 8] + lj] = ((unsigned)j << 16) | (unsigned)i;
    }
}

// pass 2: one block per digit — LDS counting sort over the digit's 256 nodes;
// emits row_start, deg2, and the padded CSR (dense writes in one segment).
__global__ __launch_bounds__(256) void pass2_csr(const unsigned* __restrict__ ebuf,
                                                 const int* __restrict__ dig_raw,
                                                 const int* __restrict__ total,
                                                 const int* __restrict__ dig_pad,
                                                 int* __restrict__ row_start,
                                                 int* __restrict__ deg2,
                                                 int* __restrict__ ent) {
    __shared__ unsigned eb[P2CAP];
    __shared__ int cnt[256], loc[256], cur[256];
    int d = blockIdx.x, t = threadIdx.x;
    int s = dig_raw[d];
    int c = total[d]; if (c > P2CAP) c = P2CAP;   // 11.7-sigma guard
    for (int i = t; i < c; i += 256) eb[i] = ebuf[s + i];
    cnt[t] = 0;
    __syncthreads();
    for (int i = t; i < c; i += 256)
        atomicAdd(&cnt[(eb[i] >> 16) & 255], 1);
    __syncthreads();
    int pc = (cnt[t] + 3) & ~3;                   // padded row size
    loc[t] = pc;
    __syncthreads();
#pragma unroll
    for (int o = 1; o < 256; o <<= 1) {
        int x = (t >= o) ? loc[t - o] : 0;
        __syncthreads();
        loc[t] += x;
        __syncthreads();
    }
    int mybase = dig_pad[d] + loc[t] - pc;        // x4-aligned
    int n = (d << 8) + t;
    if (n < N_NODES) {
        row_start[n] = mybase;
        deg2[n] = cnt[t];
    }
    cur[t] = mybase;
    __syncthreads();
    for (int i = t; i < c; i += 256) {
        unsigned v = eb[i];
        int ln = (int)(v >> 16) & 255;
        int p = atomicAdd(&cur[ln], 1);
        ent[p] = (int)(v & 0xffffu);
    }
    __syncthreads();
    if (n < N_NODES) {
        for (int p = mybase + cnt[t]; p < mybase + pc; p++)
            ent[p] = n;                            // self-pad: contributes 0
    }
}

// ---- first layer: x = relu(K1 @ xn_in), xn_in is (128, N) f32 ----------
__global__ __launch_bounds__(256) void first_layer(const float* __restrict__ xn,
                                                   const float* __restrict__ k1f,
                                                   float* __restrict__ x_cur,
                                                   float* __restrict__ x_old) {
    __shared__ float Ks[NOPEN * 129];
    __shared__ float xs[32 * 64];
    int t = threadIdx.x;
    int n0 = blockIdx.x * 64;
    for (int idx = t; idx < NOPEN * NNIN; idx += 256)
        Ks[(idx >> 7) * 129 + (idx & 127)] = k1f[idx];

    int tn = t & 15, to = t >> 4;
    float acc[4][4] = {};
    for (int c0 = 0; c0 < NNIN; c0 += 32) {
        __syncthreads();
        for (int idx = t; idx < 32 * 64; idx += 256) {
            int ci = idx >> 6, n = idx & 63;
            int gn = n0 + n;
            xs[ci * 64 + n] = (gn < N_NODES) ? xn[(size_t)(c0 + ci) * N_NODES + gn] : 0.f;
        }
        __syncthreads();
        for (int ci = 0; ci < 32; ci++) {
            float xv[4], kv[4];
#pragma unroll
            for (int i2 = 0; i2 < 4; i2++) xv[i2] = xs[ci * 64 + tn * 4 + i2];
#pragma unroll
            for (int j = 0; j < 4; j++) kv[j] = Ks[(to * 4 + j) * 129 + c0 + ci];
#pragma unroll
            for (int i2 = 0; i2 < 4; i2++)
#pragma unroll
                for (int j = 0; j < 4; j++) acc[i2][j] += xv[i2] * kv[j];
        }
    }
#pragma unroll
    for (int i2 = 0; i2 < 4; i2++) {
        int node = n0 + tn * 4 + i2;
        if (node < N_NODES) {
            float4 st;
            st.x = fmaxf(acc[i2][0], 0.f);
            st.y = fmaxf(acc[i2][1], 0.f);
            st.z = fmaxf(acc[i2][2], 0.f);
            st.w = fmaxf(acc[i2][3], 0.f);
            *(float4*)&x_cur[(size_t)node * 64 + to * 4] = st;
            *(float4*)&x_old[(size_t)node * 64 + to * 4] = st;
        }
    }
}

// ---- Y[n][o] = sum_c K[o][c] * x[n][c], fp16 out (layer 0 only) --------
__global__ __launch_bounds__(256) void mat_y(const float* __restrict__ x,
                                             const float* __restrict__ K,
                                             __half* __restrict__ Y) {
    __shared__ float Ks[64 * 65];
    __shared__ float xs[64 * 65];
    int t = threadIdx.x, n0 = blockIdx.x * 64;
    for (int idx = t; idx < 4096; idx += 256) {
        int r = idx >> 6, c = idx & 63;
        Ks[r * 65 + c] = K[idx];
        int gn = n0 + r;
        xs[r * 65 + c] = (gn < N_NODES) ? x[(size_t)gn * 64 + c] : 0.f;
    }
    __syncthreads();
    int tn = t & 15, to = t >> 4;
    float acc[4][4] = {};
    for (int c = 0; c < 64; c++) {
        float xv[4], kv[4];
#pragma unroll
        for (int i2 = 0; i2 < 4; i2++) xv[i2] = xs[(tn * 4 + i2) * 65 + c];
#pragma unroll
        for (int j = 0; j < 4; j++) kv[j] = Ks[(to * 4 + j) * 65 + c];
#pragma unroll
        for (int i2 = 0; i2 < 4; i2++)
#pragma unroll
            for (int j = 0; j < 4; j++) acc[i2][j] += xv[i2] * kv[j];
    }
#pragma unroll
    for (int i2 = 0; i2 < 4; i2++) {
        int node = n0 + tn * 4 + i2;
        if (node < N_NODES) {
            __half2 h0 = __floats2half2_rn(acc[i2][0], acc[i2][1]);
            __half2 h1 = __floats2half2_rn(acc[i2][2], acc[i2][3]);
            __half2* dst = (__half2*)&Y[(size_t)node * 64 + to * 4];
            dst[0] = h0;
            dst[1] = h1;
        }
    }
}

// ---- fused gather + update + next-layer Y (R12-proven) -----------------
__global__ __launch_bounds__(1024) void gather_update(const __half* __restrict__ Y,
                                                      const float* __restrict__ x_cur,
                                                      const float* __restrict__ x_old,
                                                      const int* __restrict__ ent,
                                                      const int* __restrict__ row_start,
                                                      const int* __restrict__ deg2,
                                                      const float* __restrict__ dinv,
                                                      const float* __restrict__ K,
                                                      const float* __restrict__ Kn,
                                                      float* __restrict__ x_out,
                                                      __half* __restrict__ Y_out) {
    __shared__ float Ks[64 * 65];    // K[c][o]-access at Ks[c*65+o]
    __shared__ float Ksn[64 * 65];   // Kn[o][c]-access at Ksn[o*65+c]
    __shared__ float Ss[16][64];
    int t = threadIdx.x;
    for (int idx = t; idx < 4096; idx += 1024) {
        Ks[(idx >> 6) * 65 + (idx & 63)] = K[idx];
        Ksn[(idx >> 6) * 65 + (idx & 63)] = Kn[idx];
    }

    int wv = t >> 6, lane = t & 63;
    int n = blockIdx.x * 16 + wv;
    int c2  = lane & 31;        // channel-pair index
    int sel = lane >> 5;        // 0: even entries, 1: odd entries
    float sx = 0.f, sy = 0.f;
    if (n < N_NODES) {
        const __half2 ynh = *(const __half2*)&Y[((size_t)n << 6) + 2 * c2];
        float ynx = __half2float(__low2half(ynh));
        float yny = __half2float(__high2half(ynh));
        float vn = dinv[n];
        int beg = __builtin_amdgcn_readfirstlane(row_start[n]);  // % 4 == 0
        int d   = __builtin_amdgcn_readfirstlane(deg2[n]);
        int end = beg + ((d + 3) & ~3);                          // padded, no tail
        for (int k = beg; k < end; k += 4) {
            int4 oo = *(const int4*)&ent[k];
            int o0 = __builtin_amdgcn_readfirstlane(oo.x);
            int o1 = __builtin_amdgcn_readfirstlane(oo.y);
            int o2 = __builtin_amdgcn_readfirstlane(oo.z);
            int o3 = __builtin_amdgcn_readfirstlane(oo.w);
            int oa = sel ? o1 : o0;
            int ob = sel ? o3 : o2;
            const __half2 ha = *(const __half2*)&Y[((size_t)oa << 6) + 2 * c2];
            const __half2 hb = *(const __half2*)&Y[((size_t)ob << 6) + 2 * c2];
            float wa = dinv[oa] * vn;
            float wb = dinv[ob] * vn;
            float ax = __half2float(__low2half(ha)), ay = __half2float(__high2half(ha));
            float bx = __half2float(__low2half(hb)), by = __half2float(__high2half(hb));
            sx += wa * ftanh(wa * (ynx - ax));
            sy += wa * ftanh(wa * (yny - ay));
            sx += wb * ftanh(wb * (ynx - bx));
            sy += wb * ftanh(wb * (yny - by));
        }
    }
    sx += __shfl_xor(sx, 32, 64);
    sy += __shfl_xor(sy, 32, 64);
    __syncthreads();            // Ks/Ksn staging complete
    if (lane < 32) {
        Ss[wv][2 * c2]     = sx;
        Ss[wv][2 * c2 + 1] = sy;
    }
    if (n < N_NODES) {
        float acc = 0.f;
#pragma unroll 8
        for (int o = 0; o < 64; o++)
            acc += Ks[lane * 65 + o] * Ss[wv][o];
        float xc = x_cur[(size_t)n * 64 + lane];
        float xo = x_old[(size_t)n * 64 + lane];
        float xnew = 2.f * xc - xo - H2 * acc;
        __builtin_nontemporal_store(xnew, &x_out[(size_t)n * 64 + lane]);
        Ss[wv][lane] = xnew;
        float acc2 = 0.f;
#pragma unroll 8
        for (int c = 0; c < 64; c++)
            acc2 += Ksn[lane * 65 + c] * Ss[wv][c];
        Y_out[((size_t)n << 6) + lane] = __float2half(acc2);
    }
}

// ---- out[n][o] = sum_c KNc[o][c] * x[n][c]; out is (N,40) f32 ----------
__global__ __launch_bounds__(256) void out_kernel(const float* __restrict__ x,
                                                  const float* __restrict__ Kc,
                                                  float* __restrict__ out) {
    __shared__ float xs[64 * 65];
    __shared__ float Ks[40 * 65];
    int t = threadIdx.x, n0 = blockIdx.x * 64;
    for (int idx = t; idx < 4096; idx += 256) {
        int r = idx >> 6, c = idx & 63;
        int gn = n0 + r;
        xs[r * 65 + c] = (gn < N_NODES) ? x[(size_t)gn * 64 + c] : 0.f;
    }
    for (int idx = t; idx < NUM_OUT * 64; idx += 256) {
        int r = idx >> 6, c = idx & 63;
        Ks[r * 65 + c] = Kc[idx];
    }
    __syncthreads();
    if (t < 160) {
        int tn = t & 15, to = t >> 4;
        float acc[4][4] = {};
        for (int c = 0; c < 64; c++) {
            float xv[4], kv[4];
#pragma unroll
            for (int i2 = 0; i2 < 4; i2++) xv[i2] = xs[(tn * 4 + i2) * 65 + c];
#pragma unroll
            for (int j = 0; j < 4; j++) kv[j] = Ks[(to * 4 + j) * 65 + c];
#pragma unroll
            for (int i2 = 0; i2 < 4; i2++)
#pragma unroll
                for (int j = 0; j < 4; j++) acc[i2][j] += xv[i2] * kv[j];
        }
#pragma unroll
        for (int i2 = 0; i2 < 4; i2++) {
            int node = n0 + tn * 4 + i2;
            if (node < N_NODES) {
#pragma unroll
                for (int j = 0; j < 4; j++)
                    out[(size_t)node * NUM_OUT + to * 4 + j] = acc[i2][j];
            }
        }
    }
}

extern "C" void kernel_launch(void* const* d_in, const int* in_sizes, int n_in,
                              void* d_out, int out_size, void* d_ws, size_t ws_size,
                              hipStream_t stream) {
    const float* xn = (const float*)d_in[0];
    const int*   I  = (const int*)d_in[1];
    const int*   J  = (const int*)d_in[2];
    const float* K1 = (const float*)d_in[4];
    const float* K2 = (const float*)d_in[5];
    const float* Kc = (const float*)d_in[6];

    const size_t NC = (size_t)N_NODES * NOPEN;  // 3.2M
    float*    f       = (float*)d_ws;
    float*    x_cur   = f;
    float*    x_old   = f + NC;
    __half*   Y0      = (__half*)(f + 2 * NC);
    __half*   Y1      = (__half*)(f + 2 * NC + NC / 2);
    float*    dinv    = f + 3 * NC;
    int*      degi    = (int*)(dinv + N_NODES);
    int*      deg2    = degi + N_NODES;
    int*      row_st  = deg2 + N_NODES;
    int*      total   = row_st + N_NODES;          // 256
    int*      dig_raw = total + 256;               // 256
    int*      dig_pad = dig_raw + 256;             // 256
    int*      bh      = dig_pad + 256;             // P1B*NDIG = 76636
    int*      off     = bh + 80000;                // NDIG*P1B = 76636
    unsigned* ebuf    = (unsigned*)(off + 80000);  // 1.6M u32
    int*      ent     = (int*)(ebuf + 2 * (size_t)N_EDGES);  // ~1.76M ints

    dim3 B(256);
    const int GN = (N_NODES + 255) / 256;   // 196

    deg_init<<<GN, B, 0, stream>>>(degi);
    count_all<<<P1B, B, 0, stream>>>(I, J, degi, bh);
    calc_dinv<<<GN, B, 0, stream>>>(degi, dinv);
    col_scan<<<NDIG, dim3(512), 0, stream>>>(bh, off, total);
    dig_scan<<<1, B, 0, stream>>>(total, dig_raw, dig_pad);
    pass1_scatter<<<P1B, B, 0, stream>>>(I, J, off, dig_raw, ebuf);
    pass2_csr<<<NDIG, B, 0, stream>>>(ebuf, dig_raw, total, dig_pad, row_st, deg2, ent);

    const int NB = (N_NODES + 63) / 64;     // 782
    first_layer<<<NB, B, 0, stream>>>(xn, K1, x_cur, x_old);
    mat_y<<<NB, B, 0, stream>>>(x_cur, K2, Y0);   // Y for layer 0 only

    __half* Yin = Y0;
    __half* Yout = Y1;
    float* xc = x_cur;
    float* xo = x_old;
    for (int l = 0; l < NLAYER; l++) {
        const float* Kl = K2 + l * NOPEN * NOPEN;
        const float* Knext = K2 + (l + 1 < NLAYER ? l + 1 : l) * NOPEN * NOPEN;
        gather_update<<<(N_NODES + 15) / 16, dim3(1024), 0, stream>>>(
            Yin, xc, xo, ent, row_st, deg2, dinv, Kl, Knext, xo, Yout);
        float* tmp = xc; xc = xo; xo = tmp;
        __half* th = Yin; Yin = Yout; Yout = th;
    }
    out_kernel<<<NB, B, 0, stream>>>(xc, Kc, (float*)d_out);
}